// Round 6
// baseline (142.991 us; speedup 1.0000x reference)
//
#include <hip/hip_runtime.h>
#include <hip/hip_bf16.h>

typedef __attribute__((ext_vector_type(8))) short short8;
typedef __attribute__((ext_vector_type(4))) float f32x4;

#define H_DIM 768
#define E_EXP 16
#define T_TASK 8
#define KSEL 4
#define L_SEQ 8192
#define B_BATCH 16
#define EW_STRIDE (768*768)

#define WCT_BLOCKS 576     // 24 x 24 tiles of 32x32
#define FILL1_BLOCKS 448   // batch 1 (25.2 MB)
#define GEMM_BLOCKS 768    // 128 m-tiles (64) x 6 n-tiles (128), n-inner
#define FILL2_BLOCKS 1280  // batches 2..15 (352.3 MB)

// ------------------------------------------------------------------ K1 ------
// blocks [0,576): inline gating (redundant, deterministic) + wct tile
// blocks [576,1024): fill batch 1 with 1.0
__global__ __launch_bounds__(256) void k1_wct_fill(
    const float* __restrict__ task_full,
    const float* __restrict__ gate_w,
    const float* __restrict__ gate_b,
    const float* __restrict__ expert_w,
    __hip_bfloat16* __restrict__ wct,
    float* __restrict__ out_tail,
    float4* __restrict__ fill_p, size_t fill_n4) {
  const int bid = blockIdx.x;
  const int tid = threadIdx.x;
  if (bid < WCT_BLOCKS) {
    __shared__ float silu_s[T_TASK * H_DIM];
    __shared__ float logits[T_TASK][E_EXP];
    __shared__ float g_sh[KSEL];
    __shared__ int   i_sh[KSEL];
    __shared__ float tile[32][33];
    const int wb = bid;
    for (int i = tid; i < T_TASK * H_DIM; i += 256) {
      float v = task_full[i];
      silu_s[i] = v / (1.f + expf(-v));
    }
    __syncthreads();
    if (tid < T_TASK * E_EXP) {
      const int t = tid >> 4, e = tid & 15;
      float a0 = 0.f, a1 = 0.f, a2 = 0.f, a3 = 0.f;
      const float* sl = &silu_s[t * H_DIM];
      for (int h = 0; h < H_DIM; h += 4) {
        a0 += sl[h]     * gate_w[(h)     * E_EXP + e];
        a1 += sl[h + 1] * gate_w[(h + 1) * E_EXP + e];
        a2 += sl[h + 2] * gate_w[(h + 2) * E_EXP + e];
        a3 += sl[h + 3] * gate_w[(h + 3) * E_EXP + e];
      }
      logits[t][e] = (a0 + a1) + (a2 + a3) + gate_b[e];
    }
    __syncthreads();
    if (tid < T_TASK) {
      const int t = tid;
      float p[E_EXP];
      float m = -1e30f;
      for (int e = 0; e < E_EXP; ++e) m = fmaxf(m, logits[t][e]);
      float s = 0.f;
      for (int e = 0; e < E_EXP; ++e) { p[e] = expf(logits[t][e] - m); s += p[e]; }
      const float inv = 1.f / s;
      for (int e = 0; e < E_EXP; ++e) p[e] *= inv;
      bool used[E_EXP];
      for (int e = 0; e < E_EXP; ++e) used[e] = false;
      float g[KSEL]; int sel[KSEL];
      for (int k = 0; k < KSEL; ++k) {
        float bv = -1.f; int bi = 0;
        for (int e = 0; e < E_EXP; ++e)
          if (!used[e] && p[e] > bv) { bv = p[e]; bi = e; }
        used[bi] = true; sel[k] = bi; g[k] = bv;
      }
      if (wb == 0) {
        for (int e = 0; e < E_EXP; ++e)
          out_tail[E_EXP + t * E_EXP + e] = used[e] ? 1.f : 0.f;
        if (t == 0)
          for (int e = 0; e < E_EXP; ++e) out_tail[e] = p[e];
      }
      if (t == 0)
        for (int k = 0; k < KSEL; ++k) { g_sh[k] = g[k]; i_sh[k] = sel[k]; }
    }
    __syncthreads();
    const float g0 = g_sh[0], g1 = g_sh[1], g2 = g_sh[2], g3 = g_sh[3];
    const size_t e0 = (size_t)i_sh[0] * EW_STRIDE;
    const size_t e1 = (size_t)i_sh[1] * EW_STRIDE;
    const size_t e2 = (size_t)i_sh[2] * EW_STRIDE;
    const size_t e3 = (size_t)i_sh[3] * EW_STRIDE;
    const int d0 = (wb % 24) * 32, o0 = (wb / 24) * 32;
    const int c = tid & 31;
    const int r0 = tid >> 5;  // 0..7
#pragma unroll
    for (int it = 0; it < 4; ++it) {
      const int rr = it * 8 + r0;  // d offset
      const size_t off = (size_t)(d0 + rr) * H_DIM + o0 + c;
      tile[rr][c] = g0 * expert_w[e0 + off] + g1 * expert_w[e1 + off] +
                    g2 * expert_w[e2 + off] + g3 * expert_w[e3 + off];
    }
    __syncthreads();
#pragma unroll
    for (int it = 0; it < 4; ++it) {
      const int rr = it * 8 + r0;  // o offset
      wct[(size_t)(o0 + rr) * H_DIM + d0 + c] = __float2bfloat16(tile[c][rr]);
    }
  } else {
    const int fb = bid - WCT_BLOCKS;
    size_t i = (size_t)fb * 256 + tid;
    const size_t stride = (size_t)FILL1_BLOCKS * 256;
    const float4 one = make_float4(1.f, 1.f, 1.f, 1.f);
    for (; i < fill_n4; i += stride) fill_p[i] = one;
  }
}

// ------------------------------------------------------------------ K2 ------
// blocks [0,768): GEMM C[l][o] = 1 + sum_d X[l][d]*wct[o][d], 64x128 tile,
//   reg-staged loads (f32 A cvt in flight), double-buffered LDS, no vmcnt
//   drains at barriers -> prefetch survives fill contention.
// blocks [768,2048): fill batches 2..15 with 1.0
#define LOADA(S, kk) { \
    const float* ap_ = X + (size_t)(m0 + ra) * H_DIM + (kk) + sa * 8; \
    S##_a0 = *(const float4*)ap_; S##_a1 = *(const float4*)(ap_ + 4); }
#define LOADB(S, kk) { \
    const __hip_bfloat16* bp_ = Bt + (size_t)(n0 + rb) * H_DIM + (kk); \
    S##_b0 = *(const short8*)(bp_ + sb * 8); \
    S##_b1 = *(const short8*)(bp_ + 16 + sb * 8); }
#define WRITEAB(S, buf) { \
    alignas(16) __hip_bfloat16 hb_[8]; \
    hb_[0] = __float2bfloat16(S##_a0.x); hb_[1] = __float2bfloat16(S##_a0.y); \
    hb_[2] = __float2bfloat16(S##_a0.z); hb_[3] = __float2bfloat16(S##_a0.w); \
    hb_[4] = __float2bfloat16(S##_a1.x); hb_[5] = __float2bfloat16(S##_a1.y); \
    hb_[6] = __float2bfloat16(S##_a1.z); hb_[7] = __float2bfloat16(S##_a1.w); \
    *(short8*)&As[buf][ra * 32 + sa * 8] = *(const short8*)hb_; \
    *(short8*)&Bs[buf][rb * 32 + sb * 8] = S##_b0; \
    *(short8*)&Bs[buf][rb * 32 + 16 + sb * 8] = S##_b1; }
#define FRAGS(buf) { \
    _Pragma("unroll") for (int i = 0; i < 2; ++i) \
      av[i] = *(const short8*)&As[buf][(arow + i * 16) * 32 + koff]; \
    _Pragma("unroll") for (int j = 0; j < 4; ++j) \
      bv[j] = *(const short8*)&Bs[buf][(brow + j * 16) * 32 + koff]; }
#define MFMAS() { \
    _Pragma("unroll") for (int i = 0; i < 2; ++i) \
      _Pragma("unroll") for (int j = 0; j < 4; ++j) \
        acc[i][j] = __builtin_amdgcn_mfma_f32_16x16x32_bf16(av[i], bv[j], acc[i][j], 0, 0, 0); }

__global__ __launch_bounds__(256) void k2_gemm_fill(
    const float* __restrict__ X,              // x[0] f32 [8192][768]
    const __hip_bfloat16* __restrict__ Bt,    // wct [768][768] (o-major)
    float* __restrict__ out,
    float4* __restrict__ fill_p, size_t fill_n4) {
  __shared__ unsigned short As[2][64 * 32];
  __shared__ unsigned short Bs[2][128 * 32];
  const int bid = blockIdx.x;
  const int tid = threadIdx.x;
  if (bid < GEMM_BLOCKS) {
    const int m0 = (bid / 6) * 64;    // n-inner: bids 6k..6k+5 share A strip
    const int n0 = (bid % 6) * 128;
    const int lane = tid & 63;
    const int w = tid >> 6;
    const int wr = w >> 1, wc = w & 1;        // 2x2 waves: 32 rows x 64 cols each
    const int ra = tid >> 2, sa = tid & 3;    // A stage: row 0..63, 8-f32 seg
    const int rb = tid >> 1, sb = tid & 1;    // B stage: row 0..127, 8-bf16 seg
    const int arow = wr * 32 + (lane & 15);
    const int brow = wc * 64 + (lane & 15);
    const int koff = (lane >> 4) * 8;         // same k map for A and B
    f32x4 acc[2][4] = {};
    float4 S0_a0, S0_a1, S1_a0, S1_a1;
    short8 S0_b0, S0_b1, S1_b0, S1_b1;
    short8 av[2], bv[4];
    LOADA(S0, 0)  LOADB(S0, 0)
    LOADA(S1, 32) LOADB(S1, 32)
    WRITEAB(S0, 0)
#pragma unroll 1
    for (int t = 0; t < 24; t += 2) {
      __syncthreads();                    // buf0 (k-step t) visible
      LOADA(S0, (t + 2) * 32)             // prefetch t+2 (tail reads spill into
      LOADB(S0, (t + 2) * 32)             //  next row / ws slack: harmless)
      FRAGS(0)
      WRITEAB(S1, 1)                      // t+1 into buf1 (loaded 1 step ago)
      MFMAS()
      __syncthreads();                    // buf1 (t+1) visible
      LOADA(S1, (t + 3) * 32)
      LOADB(S1, (t + 3) * 32)
      FRAGS(1)
      WRITEAB(S0, 0)                      // t+2 into buf0
      MFMAS()
    }
    const int crow0 = m0 + wr * 32 + (lane >> 4) * 4;
    const int ccol0 = n0 + wc * 64 + (lane & 15);
#pragma unroll
    for (int i = 0; i < 2; ++i)
#pragma unroll
      for (int j = 0; j < 4; ++j)
#pragma unroll
        for (int q = 0; q < 4; ++q)
          out[(size_t)(crow0 + i * 16 + q) * H_DIM + ccol0 + j * 16] = 1.0f + acc[i][j][q];
  } else {
    const int fb = bid - GEMM_BLOCKS;
    size_t i = (size_t)fb * 256 + tid;
    const size_t stride = (size_t)FILL2_BLOCKS * 256;
    const float4 one = make_float4(1.f, 1.f, 1.f, 1.f);
    for (; i < fill_n4; i += stride) fill_p[i] = one;
  }
}

// ---------------------------------------------------------------- launch ----
extern "C" void kernel_launch(void* const* d_in, const int* in_sizes, int n_in,
                              void* d_out, int out_size, void* d_ws, size_t ws_size,
                              hipStream_t stream) {
  const float* x         = (const float*)d_in[0];  // [16][8192][768]
  const float* task_full = (const float*)d_in[1];  // [8][768]
  const float* gate_w    = (const float*)d_in[2];  // [768][16]
  const float* gate_b    = (const float*)d_in[3];  // [16]
  const float* expert_w  = (const float*)d_in[4];  // [16][768][768]
  float* out = (float*)d_out;

  const size_t n_out_main = (size_t)B_BATCH * L_SEQ * H_DIM;  // 100663296
  float* out_tail = out + n_out_main;

  __hip_bfloat16* wct = (__hip_bfloat16*)d_ws;     // 1.18 MB (+ slack beyond)

  // K1: inline-gating + wct | fill batch 1
  const size_t fill1_n4 = (size_t)L_SEQ * H_DIM / 4;
  k1_wct_fill<<<WCT_BLOCKS + FILL1_BLOCKS, 256, 0, stream>>>(
      task_full, gate_w, gate_b, expert_w, wct, out_tail,
      (float4*)(out + (size_t)L_SEQ * H_DIM), fill1_n4);

  // K2: GEMM (reg-staged dbuf, f32 A) -> out[0] with +1.0 | fill batches 2..15
  const size_t fill2_n4 = (size_t)14 * L_SEQ * H_DIM / 4;
  k2_gemm_fill<<<GEMM_BLOCKS + FILL2_BLOCKS, 256, 0, stream>>>(
      x, wct, out,
      (float4*)(out + (size_t)2 * L_SEQ * H_DIM), fill2_n4);
}